// Round 9
// baseline (154.560 us; speedup 1.0000x reference)
//
#include <hip/hip_runtime.h>
#include <hip/hip_bf16.h>
#include <cstdint>
#include <cstddef>

// ---------- types ----------
using bf16x8 = __attribute__((ext_vector_type(8))) __bf16;
using f32x4  = __attribute__((ext_vector_type(4))) float;

__device__ __forceinline__ float b2f(unsigned short u) {
  union { unsigned u; float f; } x; x.u = ((unsigned)u) << 16; return x.f;
}
__device__ __forceinline__ unsigned short f2b(float f) {
  union { float f; unsigned u; } x; x.f = f;
  unsigned r = x.u + 0x7fffu + ((x.u >> 16) & 1u);
  return (unsigned short)(r >> 16);
}
// truncating cast: safe for P because l is computed (via MFMA) from the SAME bf16 values.
__device__ __forceinline__ unsigned short f2b_trunc(float f) {
  union { float f; unsigned u; } x; x.f = f;
  return (unsigned short)(x.u >> 16);
}

// async global->LDS, 16B per lane. dst must be wave-uniform base (HW adds lane*16).
__device__ __forceinline__ void gload_lds16(const void* g, void* l) {
  __builtin_amdgcn_global_load_lds(
      (const __attribute__((address_space(1))) void*)g,
      (__attribute__((address_space(3))) void*)l, 16, 0, 0);
}

__device__ __forceinline__ bf16x8 ldfrag(const unsigned short* p) {
  return *reinterpret_cast<const bf16x8*>(p);
}

// ---------- fused cast: x (1M float4), Wq/Wk/Wv/Wo (256K float4 each) -> bf16 ----------
__global__ __launch_bounds__(256) void cast_all_kernel(const float* __restrict__ x,
                                                       const float* __restrict__ Wq,
                                                       const float* __restrict__ Wk,
                                                       const float* __restrict__ Wv,
                                                       const float* __restrict__ Wo,
                                                       unsigned short* __restrict__ xb,
                                                       unsigned short* __restrict__ wqkv,
                                                       unsigned short* __restrict__ wob) {
  const int i = blockIdx.x * 256 + threadIdx.x;  // float4 index, total 2M
  const int XW = 1048576;                        // x: 4096*1024 floats = 1M float4
  const int WW = 262144;                         // each W: 1024*1024 floats = 256K float4
  const float* s; unsigned short* d; int j;
  if (i < XW)                { s = x;  d = xb;              j = i; }
  else if (i < XW + WW)      { s = Wq; d = wqkv;            j = i - XW; }
  else if (i < XW + 2 * WW)  { s = Wk; d = wqkv + 1048576;  j = i - XW - WW; }
  else if (i < XW + 3 * WW)  { s = Wv; d = wqkv + 2097152;  j = i - XW - 2 * WW; }
  else                       { s = Wo; d = wob;             j = i - XW - 3 * WW; }
  float4 v = reinterpret_cast<const float4*>(s)[j];
  ushort4 o;
  o.x = f2b(v.x); o.y = f2b(v.y); o.z = f2b(v.z); o.w = f2b(v.w);
  reinterpret_cast<ushort4*>(d)[j] = o;
}

__global__ __launch_bounds__(256) void sincos_kernel(float* __restrict__ st,
                                                     float* __restrict__ ct, int total) {
  int i = blockIdx.x * 256 + threadIdx.x;
  if (i >= total) return;
  int n = i >> 5, j = i & 31;
  float inv = powf(10000.0f, -(float)j * (1.0f / 32.0f));
  float ang = (float)n * inv;
  st[i] = sinf(ang);
  ct[i] = cosf(ang);
}

// ---------- 256x256 8-wave deep-pipelined GEMM (qkv projection) ----------
__global__ __launch_bounds__(512) void gemm256(const unsigned short* __restrict__ A,
                                               const unsigned short* __restrict__ B,
                                               unsigned short* __restrict__ C,
                                               const float* __restrict__ bq,
                                               const float* __restrict__ bk,
                                               const float* __restrict__ bv,
                                               int M, int N, int K, int TN) {
  extern __shared__ __align__(16) unsigned short sm[];  // [2][A 256x64 | B 256x64]
  const int tid = threadIdx.x, lane = tid & 63, wave = tid >> 6;
  const int lr = lane & 15, lk = lane >> 4;
  const int wr = wave >> 2, wc = wave & 3;  // 2 x 4 waves

  // XCD-bijective swizzle (grid % 8 == 0)
  int wg = (int)blockIdx.x;
  const int cpx = (int)gridDim.x >> 3;
  wg = (wg & 7) * cpx + (wg >> 3);
  const int bn = (wg % TN) * 256, bm = (wg / TN) * 256;

  // staging: thread t, issue i covers LDS half-rows; source pre-swizzled
  const int srow = wave * 8 + (lane >> 3);                       // + i*64 (+ h*128)
  const int scol = (((lane & 7) * 16) ^ (((lane >> 3) & 7) << 4)) >> 1;  // elems
  const unsigned short* Ag = A + (size_t)(bm + srow) * K + scol;
  const unsigned short* Bg = B + (size_t)(bn + srow) * K + scol;

  auto stage = [&](int kt, int nb) {
    const size_t ko = (size_t)kt * 64;
    unsigned short* base = sm + nb * 32768 + wave * 512;
#pragma unroll
    for (int h = 0; h < 2; ++h)
#pragma unroll
      for (int i = 0; i < 2; ++i) {
        const size_t ro = (size_t)(h * 128 + i * 64) * K + ko;
        gload_lds16(Ag + ro, base + h * 8192 + i * 4096);
        gload_lds16(Bg + ro, base + 16384 + h * 8192 + i * 4096);
      }
  };

  f32x4 acc[8][4] = {};
  const int swz = (lr & 7) << 4;  // row&7 == lr&7 for all frag rows
  const int NT = K / 64;

  stage(0, 0);
  asm volatile("s_waitcnt vmcnt(0)" ::: "memory");
  __builtin_amdgcn_s_barrier();

  for (int kt = 0; kt < NT; ++kt) {
    const int cur = kt & 1;
    if (kt + 1 < NT) stage(kt + 1, cur ^ 1);

    const unsigned short* Ab = sm + cur * 32768 + wr * 8192;
    const unsigned short* Bb = sm + cur * 32768 + 16384 + (wc >> 1) * 8192 + (wc & 1) * 4096;

    bf16x8 b[4][2];
#pragma unroll
    for (int n = 0; n < 4; ++n)
#pragma unroll
      for (int kk = 0; kk < 2; ++kk)
        b[n][kk] = ldfrag(&Bb[(n * 16 + lr) * 64 + (((kk * 64 + lk * 16) ^ swz) >> 1)]);

#pragma unroll
    for (int q = 0; q < 4; ++q) {
      bf16x8 a[2][2];
#pragma unroll
      for (int m = 0; m < 2; ++m)
#pragma unroll
        for (int kk = 0; kk < 2; ++kk)
          a[m][kk] = ldfrag(&Ab[((q * 2 + m) * 16 + lr) * 64 + (((kk * 64 + lk * 16) ^ swz) >> 1)]);
      __builtin_amdgcn_s_barrier();
      __builtin_amdgcn_s_setprio(1);
#pragma unroll
      for (int kk = 0; kk < 2; ++kk)
#pragma unroll
        for (int m = 0; m < 2; ++m)
#pragma unroll
          for (int n = 0; n < 4; ++n)
            acc[q * 2 + m][n] =
                __builtin_amdgcn_mfma_f32_16x16x32_bf16(a[m][kk], b[n][kk], acc[q * 2 + m][n], 0, 0, 0);
      __builtin_amdgcn_s_setprio(0);
      if (q < 3) __builtin_amdgcn_s_barrier();
    }
    asm volatile("s_waitcnt vmcnt(0)" ::: "memory");
    __builtin_amdgcn_s_barrier();
  }

  // epilogue: bias select per 1024-col third
#pragma unroll
  for (int n = 0; n < 4; ++n) {
    const int col = bn + wc * 64 + n * 16 + lr;
    const int third = col >> 10, ci = col & 1023;
    const float bvv = (third == 0) ? bq[ci] : (third == 1) ? bk[ci] : bv[ci];
#pragma unroll
    for (int m = 0; m < 8; ++m)
#pragma unroll
      for (int r = 0; r < 4; ++r) {
        const int row = bm + wr * 128 + m * 16 + lk * 4 + r;
        C[(size_t)row * N + col] = f2b(acc[m][n][r] + bvv);
      }
  }
}

// ---------- GEMM: C[M][N] = A[M][K] * B[N][K]^T (+bias), bf16 in, f32 acc ----------
template <int OUTF32>
__global__ __launch_bounds__(256) void gemm_bt(const unsigned short* __restrict__ A,
                                               const unsigned short* __restrict__ B,
                                               void* __restrict__ C,
                                               const float* __restrict__ bias,
                                               int M, int N, int K) {
  __shared__ __align__(16) unsigned short As[128 * 32];
  __shared__ __align__(16) unsigned short Bs[128 * 32];
  const int tid = threadIdx.x;
  const int lane = tid & 63, wave = tid >> 6;
  const int wr = wave >> 1, wc = wave & 1;
  const int bm = blockIdx.y * 128, bn = blockIdx.x * 128;
  const int lr = lane & 15, lk = lane >> 4;
  f32x4 acc[4][4] = {};

  for (int k0 = 0; k0 < K; k0 += 32) {
#pragma unroll
    for (int i = 0; i < 2; ++i) {
      int idx = i * 256 + tid;
      int row = idx >> 2, c8 = (idx & 3) * 8;
      gload_lds16(A + (size_t)(bm + row) * K + k0 + c8, &As[(i * 256 + wave * 64) * 8]);
      gload_lds16(B + (size_t)(bn + row) * K + k0 + c8, &Bs[(i * 256 + wave * 64) * 8]);
    }
    __syncthreads();
    bf16x8 af[4], bfr[4];
#pragma unroll
    for (int mi = 0; mi < 4; ++mi)
      af[mi] = ldfrag(&As[(wr * 64 + mi * 16 + lr) * 32 + lk * 8]);
#pragma unroll
    for (int ni = 0; ni < 4; ++ni)
      bfr[ni] = ldfrag(&Bs[(wc * 64 + ni * 16 + lr) * 32 + lk * 8]);
#pragma unroll
    for (int mi = 0; mi < 4; ++mi)
#pragma unroll
      for (int ni = 0; ni < 4; ++ni)
        acc[mi][ni] = __builtin_amdgcn_mfma_f32_16x16x32_bf16(af[mi], bfr[ni], acc[mi][ni], 0, 0, 0);
    __syncthreads();
  }

#pragma unroll
  for (int mi = 0; mi < 4; ++mi) {
#pragma unroll
    for (int ni = 0; ni < 4; ++ni) {
      int col = bn + wc * 64 + ni * 16 + lr;
      float bv = bias ? bias[col] : 0.0f;
#pragma unroll
      for (int r = 0; r < 4; ++r) {
        int row = bm + wr * 64 + mi * 16 + lk * 4 + r;
        float v = acc[mi][ni][r] + bv;
        if (OUTF32)
          reinterpret_cast<float*>(C)[(size_t)row * N + col] = v;
        else
          reinterpret_cast<unsigned short*>(C)[(size_t)row * N + col] = f2b(v);
      }
    }
  }
}

// ---------- RoPE: qkv[B*N][3072] -> Qo/Ko [B*16][N][64] ----------
// q pre-scaled by log2(e)/sqrt(D) so flash softmax runs in exp2 space.
__global__ __launch_bounds__(256) void rope_kernel(const unsigned short* __restrict__ qkv,
                                                   const float* __restrict__ st,
                                                   const float* __restrict__ ct,
                                                   unsigned short* __restrict__ Qo,
                                                   unsigned short* __restrict__ Ko, int N) {
  const int lane = threadIdx.x & 63;
  const int gw = (int)((blockIdx.x * 256 + threadIdx.x) >> 6);
  const int total = 2 * 2 * N * 16;
  if (gw >= total) return;
  const int which = gw / (2 * N * 16);  // 0=q, 1=k
  int rem = gw - which * (2 * N * 16);
  const int b = rem / (N * 16);
  rem -= b * (N * 16);
  const int n = rem >> 4, h = rem & 15;
  const int d = lane;
  float v = b2f(qkv[((size_t)(b * N + n)) * 3072 + which * 1024 + h * 64 + d]);
  const int j = d & 31;
  float c = ct[n * 32 + j], s = st[n * 32 + j];
  int partner = (d < 32) ? (2 * d + 1) : (2 * (d - 32));
  float pv = __shfl(v, partner, 64);
  float res = (d < 32) ? (v * c - pv * s) : (v * c + pv * s);
  if (which == 0) res *= 0.18033688f;  // (1/8) * log2(e)
  unsigned short* dst = which ? Ko : Qo;
  dst[(((size_t)(b * 16 + h)) * N + n) * 64 + d] = f2b(res);
}

// ---------- V transpose: qkv v-part [n][d] -> Vt[bh][d][n] ----------
__global__ __launch_bounds__(256) void vtrans_kernel(const unsigned short* __restrict__ qkv,
                                                     unsigned short* __restrict__ Vt, int N) {
  __shared__ __align__(16) unsigned short T[64][80];
  const int bh = blockIdx.y, b = bh >> 4, h = bh & 15;
  const int n0 = blockIdx.x * 64;
  const int tid = threadIdx.x;
#pragma unroll
  for (int i = 0; i < 2; ++i) {
    int idx = i * 256 + tid;
    int row = idx >> 3, c8 = (idx & 7) * 8;
    int4 v = *reinterpret_cast<const int4*>(
        &qkv[((size_t)(b * N + n0 + row)) * 3072 + 2048 + h * 64 + c8]);
    *reinterpret_cast<int4*>(&T[row][c8]) = v;
  }
  __syncthreads();
#pragma unroll
  for (int i = 0; i < 2; ++i) {
    int idx = i * 256 + tid;
    int d = idx >> 3, n8 = (idx & 7) * 8;
    int4 ov;
    ov.x = (int)T[n8 + 0][d] | ((int)T[n8 + 1][d] << 16);
    ov.y = (int)T[n8 + 2][d] | ((int)T[n8 + 3][d] << 16);
    ov.z = (int)T[n8 + 4][d] | ((int)T[n8 + 5][d] << 16);
    ov.w = (int)T[n8 + 6][d] | ((int)T[n8 + 7][d] << 16);
    *reinterpret_cast<int4*>(&Vt[((size_t)bh * 64 + d) * N + n0 + n8]) = ov;
  }
}

// ---------- Flash attention ----------
// Q/K [bh][N][64] (q pre-scaled, exp2 space), Vt [bh][64][N] -> Out bf16 [B][N][1024]
// 256 threads = 4 waves, 16 q-rows/wave = one 64-row q-tile per scan; KVBLK=128.
// Sequential dual-tile pairing over 64-row tiles (x, 31-x): 17 uniform phases.
// Grid = 512 blocks, LDS = 80KB -> 2 INDEPENDENT blocks/CU (no shared barrier):
// one block's MFMA fills the other's softmax/staging stalls.
// XCD-pinned mapping: XCD c = id&7 serves bh in {4c..4c+3} -> per-XCD K/V
// working set 2MB <= 4MB L2 (k-tile re-reads become L2 hits).
__global__ __launch_bounds__(256) void flash_kernel(const unsigned short* __restrict__ Q,
                                                    const unsigned short* __restrict__ Kb,
                                                    const unsigned short* __restrict__ Vt,
                                                    unsigned short* __restrict__ Out, int N) {
  extern __shared__ __align__(16) unsigned short smem[];
  unsigned short* KsB = smem;           // [2][128*64]
  unsigned short* VsB = smem + 16384;   // [2][64*128]
  unsigned short* PsB = smem + 32768;   // [4][16*128]

  const int tid = threadIdx.x;
  const int lane = tid & 63, wave = tid >> 6;      // wave 0..3
  const int lr = lane & 15, lk = lane >> 4;
  // XCD-pinned block mapping (assumes XCD = linear_id % 8 round-robin)
  const int id = (int)blockIdx.x;                  // 0..511
  const int c8 = id & 7, j8 = id >> 3;             // j8 0..63
  const int bh = c8 * 4 + (j8 >> 4);
  const int x  = j8 & 15;                          // 0..15
  const int qtA = x, qtB = 31 - x;                 // 64-row tile indices
  const int ntA = (x >> 1) + 1;                    // + ntB = 17 phases, uniform
  const int moffA = (x & 1) * 64;
  const int moffB = 64 - moffA;                    // (31-x)&1 = 1-(x&1)
  const unsigned short* Qh = Q + (size_t)bh * N * 64;
  const unsigned short* Kh = Kb + (size_t)bh * N * 64;
  const unsigned short* Vh = Vt + (size_t)bh * 64 * N;
  unsigned short* Pw = PsB + wave * 2048;

  const int wrowA = qtA * 64 + wave * 16;
  const int wrowB = qtB * 64 + wave * 16;

  // per-thread staging sources (pre-swizzled to match gload_lds linear dst):
  // K: issue i covers LDS rows [i*32, i*32+32); thread -> row tid>>3, chunk tid&7.
  // V: issue i covers LDS rows [i*16, i*16+16); thread -> row tid>>4, chunk tid&15.
  // Row advance per issue (32 / 16) keeps row&7 invariant -> swizzle per-thread const.
  const int kr0 = tid >> 3;                                       // 0..31
  const int kc0 = (((tid & 7) * 16) ^ ((kr0 & 7) << 4)) >> 1;
  const unsigned short* Kg0 = Kh + (size_t)kr0 * 64 + kc0;
  const int vr0 = tid >> 4;                                       // 0..15
  const int vc0 = (((tid & 15) * 16) ^ ((vr0 & 7) << 4)) >> 1;
  const unsigned short* Vg0 = Vh + (size_t)vr0 * N + vc0;

  auto stage = [&](int buf, int tk) {
    const unsigned short* kp = Kg0 + (size_t)tk * 8192;   // +128 rows * 64
    const unsigned short* vp = Vg0 + (size_t)tk * 128;    // +128 cols
    unsigned short* kl = KsB + buf * 8192 + wave * 512;
    unsigned short* vl = VsB + buf * 8192 + wave * 512;
#pragma unroll
    for (int i = 0; i < 4; ++i) {
      gload_lds16(kp + (size_t)i * 2048, kl + i * 2048);        // +32 K rows each
      gload_lds16(vp + (size_t)i * 16 * N, vl + i * 2048);      // +16 V rows each
    }
  };

  stage(0, 0);

  bf16x8 qA0 = ldfrag(&Qh[(size_t)(wrowA + lr) * 64 + lk * 8]);
  bf16x8 qA1 = ldfrag(&Qh[(size_t)(wrowA + lr) * 64 + 32 + lk * 8]);
  bf16x8 qB0 = ldfrag(&Qh[(size_t)(wrowB + lr) * 64 + lk * 8]);
  bf16x8 qB1 = ldfrag(&Qh[(size_t)(wrowB + lr) * 64 + 32 + lk * 8]);

  bf16x8 ones;
  {
    union { unsigned short u; __bf16 b; } one; one.u = 0x3F80;
#pragma unroll
    for (int j = 0; j < 8; ++j) ones[j] = one.b;
  }

  f32x4 oacc[4] = {};
  f32x4 lacc = {};
  float m_run[4];
#pragma unroll
  for (int r = 0; r < 4; ++r) m_run[r] = -INFINITY;

  // one k-phase: QK^T (16 MFMA) -> online softmax -> P (LDS) -> PV + l-sum (20 MFMA)
  auto compute_phase = [&](int buf, bf16x8 q0, bf16x8 q1, bool diag, int moff) {
    const unsigned short* Ksb = KsB + buf * 8192;
    const unsigned short* Vsb = VsB + buf * 8192;
    f32x4 s[8];
#pragma unroll
    for (int ni = 0; ni < 8; ++ni) s[ni] = f32x4{0.f, 0.f, 0.f, 0.f};

    __builtin_amdgcn_s_setprio(1);
#pragma unroll
    for (int ni = 0; ni < 8; ++ni) {
      const int R = ni * 16 + lr;
      const int sw = (R & 7) << 4;
      bf16x8 kf0 = ldfrag(&Ksb[R * 64 + (((lk * 16) ^ sw) >> 1)]);
      bf16x8 kf1 = ldfrag(&Ksb[R * 64 + (((64 + lk * 16) ^ sw) >> 1)]);
      s[ni] = __builtin_amdgcn_mfma_f32_16x16x32_bf16(q0, kf0, s[ni], 0, 0, 0);
      s[ni] = __builtin_amdgcn_mfma_f32_16x16x32_bf16(q1, kf1, s[ni], 0, 0, 0);
    }
    __builtin_amdgcn_s_setprio(0);

    if (diag) {  // tile-local causal: col ni*16+lr vs row (wave*16+lk*4+r)+moff
      const int qrow = wave * 16 + lk * 4 + moff;
#pragma unroll
      for (int ni = 0; ni < 8; ++ni)
#pragma unroll
        for (int r = 0; r < 4; ++r)
          if (ni * 16 + lr > qrow + r) s[ni][r] = -INFINITY;
    }

    float pmax[4];
    bool okl = true;
#pragma unroll
    for (int r = 0; r < 4; ++r) {
      float mx = s[0][r];
#pragma unroll
      for (int ni = 1; ni < 8; ++ni) mx = fmaxf(mx, s[ni][r]);
#pragma unroll
      for (int off = 1; off < 16; off <<= 1) mx = fmaxf(mx, __shfl_xor(mx, off, 64));
      pmax[r] = mx;
      okl = okl && (mx - m_run[r] <= 8.0f);
    }
    if (!__all(okl)) {  // rescale path (rare)
#pragma unroll
      for (int r = 0; r < 4; ++r) {
        float nm = fmaxf(m_run[r], pmax[r]);
        float alpha = __builtin_amdgcn_exp2f(m_run[r] - nm);
        m_run[r] = nm;
#pragma unroll
        for (int ni = 0; ni < 4; ++ni) oacc[ni][r] *= alpha;
        lacc[r] *= alpha;
      }
    }
    // P = exp2(s - m) -> bf16 (trunc) -> swizzled per-wave LDS [16][128]
#pragma unroll
    for (int ni = 0; ni < 8; ++ni)
#pragma unroll
      for (int r = 0; r < 4; ++r) {
        float p = __builtin_amdgcn_exp2f(s[ni][r] - m_run[r]);
        int row = lk * 4 + r;
        int colb = (ni * 16 + lr) * 2;
        Pw[row * 128 + ((colb ^ ((row & 7) << 4)) >> 1)] = f2b_trunc(p);
      }

    // O += P @ V ; l += P @ ones
    __builtin_amdgcn_s_setprio(1);
#pragma unroll
    for (int kc = 0; kc < 4; ++kc) {
      const int cb = kc * 64 + lk * 16;
      bf16x8 pf = ldfrag(&Pw[lr * 128 + ((cb ^ ((lr & 7) << 4)) >> 1)]);
      lacc = __builtin_amdgcn_mfma_f32_16x16x32_bf16(pf, ones, lacc, 0, 0, 0);
#pragma unroll
      for (int ni = 0; ni < 4; ++ni) {
        const int RV = ni * 16 + lr;
        bf16x8 vf = ldfrag(&Vsb[RV * 128 + ((cb ^ ((RV & 7) << 4)) >> 1)]);
        oacc[ni] = __builtin_amdgcn_mfma_f32_16x16x32_bf16(pf, vf, oacc[ni], 0, 0, 0);
      }
    }
    __builtin_amdgcn_s_setprio(0);
  };

  const int b = bh >> 4, h = bh & 15;
  auto epilogue = [&](int wrow0) {
    float rl[4];
#pragma unroll
    for (int r = 0; r < 4; ++r) rl[r] = 1.0f / lacc[r];
#pragma unroll
    for (int ni = 0; ni < 4; ++ni)
#pragma unroll
      for (int r = 0; r < 4; ++r) {
        float v = oacc[ni][r] * rl[r];
        int n = wrow0 + lk * 4 + r;
        Out[((size_t)(b * N + n)) * 1024 + h * 64 + ni * 16 + lr] = f2b(v);
      }
  };

  __syncthreads();

  int buf = 0;
  for (int p = 0; p < 17; ++p) {
    if (p + 1 < 17) {
      int tk2 = (p + 1 < ntA) ? (p + 1) : (p + 1 - ntA);
      stage(buf ^ 1, tk2);
    }
    if (p == ntA) {  // scan A done: write O_A, reset accumulators
      epilogue(wrowA);
#pragma unroll
      for (int ni = 0; ni < 4; ++ni) oacc[ni] = f32x4{0.f, 0.f, 0.f, 0.f};
      lacc = f32x4{0.f, 0.f, 0.f, 0.f};
#pragma unroll
      for (int r = 0; r < 4; ++r) m_run[r] = -INFINITY;
    }
    if (p < ntA) compute_phase(buf, qA0, qA1, p == ntA - 1, moffA);
    else         compute_phase(buf, qB0, qB1, p == 16, moffB);
    __syncthreads();
    buf ^= 1;
  }
  epilogue(wrowB);
}

// ---------- launch ----------
extern "C" void kernel_launch(void* const* d_in, const int* in_sizes, int n_in,
                              void* d_out, int out_size, void* d_ws, size_t ws_size,
                              hipStream_t stream) {
  const int B = 2, N = 2048, E = 1024, C = 1024, NC = 3072;
  const int M = B * N;  // 4096

  const float* x  = (const float*)d_in[0];
  const float* Wq = (const float*)d_in[1];
  const float* bq = (const float*)d_in[2];
  const float* Wk = (const float*)d_in[3];
  const float* bk = (const float*)d_in[4];
  const float* Wv = (const float*)d_in[5];
  const float* bv = (const float*)d_in[6];
  const float* Wo = (const float*)d_in[7];
  const float* bo = (const float*)d_in[8];

  char* w = (char*)d_ws;
  size_t off = 0;
  auto alloc = [&](size_t bytes) {
    void* p = w + off;
    off += (bytes + 255) & ~(size_t)255;
    return p;
  };
  unsigned short* xb    = (unsigned short*)alloc((size_t)M * E * 2);
  unsigned short* wqkv  = (unsigned short*)alloc((size_t)NC * E * 2);
  unsigned short* wob   = (unsigned short*)alloc((size_t)E * C * 2);
  unsigned short* qkvb  = (unsigned short*)alloc((size_t)M * NC * 2);
  unsigned short* qb    = (unsigned short*)alloc((size_t)B * 16 * N * 64 * 2);
  unsigned short* kb    = (unsigned short*)alloc((size_t)B * 16 * N * 64 * 2);
  unsigned short* vt    = (unsigned short*)alloc((size_t)B * 16 * 64 * N * 2);
  unsigned short* attnb = (unsigned short*)alloc((size_t)M * C * 2);
  float* sin_t = (float*)alloc((size_t)N * 32 * 4);
  float* cos_t = (float*)alloc((size_t)N * 32 * 4);

  // fused bf16 casts (x, Wq, Wk, Wv, Wo) — one kernel, 2M float4 total
  cast_all_kernel<<<8192, 256, 0, stream>>>(x, Wq, Wk, Wv, Wo, xb, wqkv, wob);

  int n3 = N * 32;
  sincos_kernel<<<(n3 + 255) / 256, 256, 0, stream>>>(sin_t, cos_t, n3);

  // QKV projection: 256^2 deep-pipelined GEMM, bias select in epilogue
  static const int GEMM_LDS = 131072;
  hipFuncSetAttribute(reinterpret_cast<const void*>(gemm256),
                      hipFuncAttributeMaxDynamicSharedMemorySize, GEMM_LDS);
  gemm256<<<dim3((NC / 256) * (M / 256)), 512, GEMM_LDS, stream>>>(
      xb, wqkv, qkvb, bq, bk, bv, M, NC, E, NC / 256);

  // RoPE + layout to [bh][N][64]
  int nwaves = 2 * B * N * 16;
  rope_kernel<<<nwaves / 4, 256, 0, stream>>>(qkvb, sin_t, cos_t, qb, kb, N);

  // V transpose to [bh][64][N]
  vtrans_kernel<<<dim3(N / 64, B * 16), 256, 0, stream>>>(qkvb, vt, N);

  // causal flash attention: 512 blocks x 256 thr, 80KB LDS -> 2 blocks/CU
  static const int FLASH_LDS = 81920;
  hipFuncSetAttribute(reinterpret_cast<const void*>(flash_kernel),
                      hipFuncAttributeMaxDynamicSharedMemorySize, FLASH_LDS);
  flash_kernel<<<512, 256, FLASH_LDS, stream>>>(qb, kb, vt, attnb, N);

  // output projection: [4096][1024] x [1024][1024]^T + bo -> f32 d_out
  gemm_bt<1><<<dim3(E / 128, M / 128), 256, 0, stream>>>(attnb, wob, d_out, bo, M, E, C);
}

// Round 11
// 138.140 us; speedup vs baseline: 1.1189x; 1.1189x over previous
//
#include <hip/hip_runtime.h>
#include <hip/hip_bf16.h>
#include <cstdint>
#include <cstddef>

// ---------- types ----------
using bf16x8 = __attribute__((ext_vector_type(8))) __bf16;
using f32x4  = __attribute__((ext_vector_type(4))) float;

__device__ __forceinline__ float b2f(unsigned short u) {
  union { unsigned u; float f; } x; x.u = ((unsigned)u) << 16; return x.f;
}
__device__ __forceinline__ unsigned short f2b(float f) {
  union { float f; unsigned u; } x; x.f = f;
  unsigned r = x.u + 0x7fffu + ((x.u >> 16) & 1u);
  return (unsigned short)(r >> 16);
}
// truncating cast: safe for P because l is computed (via MFMA) from the SAME bf16 values.
__device__ __forceinline__ unsigned short f2b_trunc(float f) {
  union { float f; unsigned u; } x; x.f = f;
  return (unsigned short)(x.u >> 16);
}

// async global->LDS, 16B per lane. dst must be wave-uniform base (HW adds lane*16).
__device__ __forceinline__ void gload_lds16(const void* g, void* l) {
  __builtin_amdgcn_global_load_lds(
      (const __attribute__((address_space(1))) void*)g,
      (__attribute__((address_space(3))) void*)l, 16, 0, 0);
}

__device__ __forceinline__ bf16x8 ldfrag(const unsigned short* p) {
  return *reinterpret_cast<const bf16x8*>(p);
}

// ---------- fused cast: x (1M float4), Wq/Wk/Wv/Wo (256K float4 each) -> bf16 ----------
__global__ __launch_bounds__(256) void cast_all_kernel(const float* __restrict__ x,
                                                       const float* __restrict__ Wq,
                                                       const float* __restrict__ Wk,
                                                       const float* __restrict__ Wv,
                                                       const float* __restrict__ Wo,
                                                       unsigned short* __restrict__ xb,
                                                       unsigned short* __restrict__ wqkv,
                                                       unsigned short* __restrict__ wob) {
  const int i = blockIdx.x * 256 + threadIdx.x;  // float4 index, total 2M
  const int XW = 1048576;                        // x: 4096*1024 floats = 1M float4
  const int WW = 262144;                         // each W: 1024*1024 floats = 256K float4
  const float* s; unsigned short* d; int j;
  if (i < XW)                { s = x;  d = xb;              j = i; }
  else if (i < XW + WW)      { s = Wq; d = wqkv;            j = i - XW; }
  else if (i < XW + 2 * WW)  { s = Wk; d = wqkv + 1048576;  j = i - XW - WW; }
  else if (i < XW + 3 * WW)  { s = Wv; d = wqkv + 2097152;  j = i - XW - 2 * WW; }
  else                       { s = Wo; d = wob;             j = i - XW - 3 * WW; }
  float4 v = reinterpret_cast<const float4*>(s)[j];
  ushort4 o;
  o.x = f2b(v.x); o.y = f2b(v.y); o.z = f2b(v.z); o.w = f2b(v.w);
  reinterpret_cast<ushort4*>(d)[j] = o;
}

__global__ __launch_bounds__(256) void sincos_kernel(float* __restrict__ st,
                                                     float* __restrict__ ct, int total) {
  int i = blockIdx.x * 256 + threadIdx.x;
  if (i >= total) return;
  int n = i >> 5, j = i & 31;
  float inv = powf(10000.0f, -(float)j * (1.0f / 32.0f));
  float ang = (float)n * inv;
  st[i] = sinf(ang);
  ct[i] = cosf(ang);
}

// ---------- 256x256 8-wave deep-pipelined GEMM (qkv projection) ----------
__global__ __launch_bounds__(512) void gemm256(const unsigned short* __restrict__ A,
                                               const unsigned short* __restrict__ B,
                                               unsigned short* __restrict__ C,
                                               const float* __restrict__ bq,
                                               const float* __restrict__ bk,
                                               const float* __restrict__ bv,
                                               int M, int N, int K, int TN) {
  extern __shared__ __align__(16) unsigned short sm[];  // [2][A 256x64 | B 256x64]
  const int tid = threadIdx.x, lane = tid & 63, wave = tid >> 6;
  const int lr = lane & 15, lk = lane >> 4;
  const int wr = wave >> 2, wc = wave & 3;  // 2 x 4 waves

  // XCD-bijective swizzle (grid % 8 == 0)
  int wg = (int)blockIdx.x;
  const int cpx = (int)gridDim.x >> 3;
  wg = (wg & 7) * cpx + (wg >> 3);
  const int bn = (wg % TN) * 256, bm = (wg / TN) * 256;

  // staging: thread t, issue i covers LDS half-rows; source pre-swizzled
  const int srow = wave * 8 + (lane >> 3);                       // + i*64 (+ h*128)
  const int scol = (((lane & 7) * 16) ^ (((lane >> 3) & 7) << 4)) >> 1;  // elems
  const unsigned short* Ag = A + (size_t)(bm + srow) * K + scol;
  const unsigned short* Bg = B + (size_t)(bn + srow) * K + scol;

  auto stage = [&](int kt, int nb) {
    const size_t ko = (size_t)kt * 64;
    unsigned short* base = sm + nb * 32768 + wave * 512;
#pragma unroll
    for (int h = 0; h < 2; ++h)
#pragma unroll
      for (int i = 0; i < 2; ++i) {
        const size_t ro = (size_t)(h * 128 + i * 64) * K + ko;
        gload_lds16(Ag + ro, base + h * 8192 + i * 4096);
        gload_lds16(Bg + ro, base + 16384 + h * 8192 + i * 4096);
      }
  };

  f32x4 acc[8][4] = {};
  const int swz = (lr & 7) << 4;  // row&7 == lr&7 for all frag rows
  const int NT = K / 64;

  stage(0, 0);
  asm volatile("s_waitcnt vmcnt(0)" ::: "memory");
  __builtin_amdgcn_s_barrier();

  for (int kt = 0; kt < NT; ++kt) {
    const int cur = kt & 1;
    if (kt + 1 < NT) stage(kt + 1, cur ^ 1);

    const unsigned short* Ab = sm + cur * 32768 + wr * 8192;
    const unsigned short* Bb = sm + cur * 32768 + 16384 + (wc >> 1) * 8192 + (wc & 1) * 4096;

    bf16x8 b[4][2];
#pragma unroll
    for (int n = 0; n < 4; ++n)
#pragma unroll
      for (int kk = 0; kk < 2; ++kk)
        b[n][kk] = ldfrag(&Bb[(n * 16 + lr) * 64 + (((kk * 64 + lk * 16) ^ swz) >> 1)]);

#pragma unroll
    for (int q = 0; q < 4; ++q) {
      bf16x8 a[2][2];
#pragma unroll
      for (int m = 0; m < 2; ++m)
#pragma unroll
        for (int kk = 0; kk < 2; ++kk)
          a[m][kk] = ldfrag(&Ab[((q * 2 + m) * 16 + lr) * 64 + (((kk * 64 + lk * 16) ^ swz) >> 1)]);
      __builtin_amdgcn_s_barrier();
      __builtin_amdgcn_s_setprio(1);
#pragma unroll
      for (int kk = 0; kk < 2; ++kk)
#pragma unroll
        for (int m = 0; m < 2; ++m)
#pragma unroll
          for (int n = 0; n < 4; ++n)
            acc[q * 2 + m][n] =
                __builtin_amdgcn_mfma_f32_16x16x32_bf16(a[m][kk], b[n][kk], acc[q * 2 + m][n], 0, 0, 0);
      __builtin_amdgcn_s_setprio(0);
      if (q < 3) __builtin_amdgcn_s_barrier();
    }
    asm volatile("s_waitcnt vmcnt(0)" ::: "memory");
    __builtin_amdgcn_s_barrier();
  }

  // epilogue: bias select per 1024-col third
#pragma unroll
  for (int n = 0; n < 4; ++n) {
    const int col = bn + wc * 64 + n * 16 + lr;
    const int third = col >> 10, ci = col & 1023;
    const float bvv = (third == 0) ? bq[ci] : (third == 1) ? bk[ci] : bv[ci];
#pragma unroll
    for (int m = 0; m < 8; ++m)
#pragma unroll
      for (int r = 0; r < 4; ++r) {
        const int row = bm + wr * 128 + m * 16 + lk * 4 + r;
        C[(size_t)row * N + col] = f2b(acc[m][n][r] + bvv);
      }
  }
}

// ---------- GEMM: C[M][N] = A[M][K] * B[N][K]^T (+bias), bf16 in, f32 acc ----------
template <int OUTF32>
__global__ __launch_bounds__(256) void gemm_bt(const unsigned short* __restrict__ A,
                                               const unsigned short* __restrict__ B,
                                               void* __restrict__ C,
                                               const float* __restrict__ bias,
                                               int M, int N, int K) {
  __shared__ __align__(16) unsigned short As[128 * 32];
  __shared__ __align__(16) unsigned short Bs[128 * 32];
  const int tid = threadIdx.x;
  const int lane = tid & 63, wave = tid >> 6;
  const int wr = wave >> 1, wc = wave & 1;
  const int bm = blockIdx.y * 128, bn = blockIdx.x * 128;
  const int lr = lane & 15, lk = lane >> 4;
  f32x4 acc[4][4] = {};

  for (int k0 = 0; k0 < K; k0 += 32) {
#pragma unroll
    for (int i = 0; i < 2; ++i) {
      int idx = i * 256 + tid;
      int row = idx >> 2, c8 = (idx & 3) * 8;
      gload_lds16(A + (size_t)(bm + row) * K + k0 + c8, &As[(i * 256 + wave * 64) * 8]);
      gload_lds16(B + (size_t)(bn + row) * K + k0 + c8, &Bs[(i * 256 + wave * 64) * 8]);
    }
    __syncthreads();
    bf16x8 af[4], bfr[4];
#pragma unroll
    for (int mi = 0; mi < 4; ++mi)
      af[mi] = ldfrag(&As[(wr * 64 + mi * 16 + lr) * 32 + lk * 8]);
#pragma unroll
    for (int ni = 0; ni < 4; ++ni)
      bfr[ni] = ldfrag(&Bs[(wc * 64 + ni * 16 + lr) * 32 + lk * 8]);
#pragma unroll
    for (int mi = 0; mi < 4; ++mi)
#pragma unroll
      for (int ni = 0; ni < 4; ++ni)
        acc[mi][ni] = __builtin_amdgcn_mfma_f32_16x16x32_bf16(af[mi], bfr[ni], acc[mi][ni], 0, 0, 0);
    __syncthreads();
  }

#pragma unroll
  for (int mi = 0; mi < 4; ++mi) {
#pragma unroll
    for (int ni = 0; ni < 4; ++ni) {
      int col = bn + wc * 64 + ni * 16 + lr;
      float bv = bias ? bias[col] : 0.0f;
#pragma unroll
      for (int r = 0; r < 4; ++r) {
        int row = bm + wr * 64 + mi * 16 + lk * 4 + r;
        float v = acc[mi][ni][r] + bv;
        if (OUTF32)
          reinterpret_cast<float*>(C)[(size_t)row * N + col] = v;
        else
          reinterpret_cast<unsigned short*>(C)[(size_t)row * N + col] = f2b(v);
      }
    }
  }
}

// ---------- RoPE: qkv[B*N][3072] -> Qo/Ko [B*16][N][64] ----------
// q pre-scaled by log2(e)/sqrt(D) so flash softmax runs in exp2 space.
__global__ __launch_bounds__(256) void rope_kernel(const unsigned short* __restrict__ qkv,
                                                   const float* __restrict__ st,
                                                   const float* __restrict__ ct,
                                                   unsigned short* __restrict__ Qo,
                                                   unsigned short* __restrict__ Ko, int N) {
  const int lane = threadIdx.x & 63;
  const int gw = (int)((blockIdx.x * 256 + threadIdx.x) >> 6);
  const int total = 2 * 2 * N * 16;
  if (gw >= total) return;
  const int which = gw / (2 * N * 16);  // 0=q, 1=k
  int rem = gw - which * (2 * N * 16);
  const int b = rem / (N * 16);
  rem -= b * (N * 16);
  const int n = rem >> 4, h = rem & 15;
  const int d = lane;
  float v = b2f(qkv[((size_t)(b * N + n)) * 3072 + which * 1024 + h * 64 + d]);
  const int j = d & 31;
  float c = ct[n * 32 + j], s = st[n * 32 + j];
  int partner = (d < 32) ? (2 * d + 1) : (2 * (d - 32));
  float pv = __shfl(v, partner, 64);
  float res = (d < 32) ? (v * c - pv * s) : (v * c + pv * s);
  if (which == 0) res *= 0.18033688f;  // (1/8) * log2(e)
  unsigned short* dst = which ? Ko : Qo;
  dst[(((size_t)(b * 16 + h)) * N + n) * 64 + d] = f2b(res);
}

// ---------- V transpose: qkv v-part [n][d] -> Vt[bh][d][n'] ----------
// Columns sigma-permuted within each 32-block: k = 16a + 4m + b  ->  col' = 8m + 4a + b.
// This makes flash's PV B-fragment (P, kept in registers) and A-fragment (V from LDS)
// agree on contraction order with ZERO cross-lane data movement.
__global__ __launch_bounds__(256) void vtrans_kernel(const unsigned short* __restrict__ qkv,
                                                     unsigned short* __restrict__ Vt, int N) {
  __shared__ __align__(16) unsigned short T[64][80];
  const int bh = blockIdx.y, b = bh >> 4, h = bh & 15;
  const int n0 = blockIdx.x * 64;
  const int tid = threadIdx.x;
#pragma unroll
  for (int i = 0; i < 2; ++i) {
    int idx = i * 256 + tid;
    int row = idx >> 3, c8 = (idx & 7) * 8;
    int4 v = *reinterpret_cast<const int4*>(
        &qkv[((size_t)(b * N + n0 + row)) * 3072 + 2048 + h * 64 + c8]);
    *reinterpret_cast<int4*>(&T[row][c8]) = v;
  }
  __syncthreads();
#pragma unroll
  for (int i = 0; i < 2; ++i) {
    int idx = i * 256 + tid;
    int d = idx >> 3, n8 = (idx & 7) * 8;
    int4 ov;
    ov.x = (int)T[n8 + 0][d] | ((int)T[n8 + 1][d] << 16);
    ov.y = (int)T[n8 + 2][d] | ((int)T[n8 + 3][d] << 16);
    ov.z = (int)T[n8 + 4][d] | ((int)T[n8 + 5][d] << 16);
    ov.w = (int)T[n8 + 6][d] | ((int)T[n8 + 7][d] << 16);
    // sigma-permuted destination: t=0..3 -> C0..C0+3 ; t=4..7 -> C1..C1+3
    const int a = (n8 >> 4) & 1, m0 = (n8 >> 2) & 3, b32 = n8 & 32;
    const int C0 = n0 + b32 + m0 * 8 + a * 4;
    const int C1 = C0 + 8;
    unsigned short* dst = &Vt[((size_t)bh * 64 + d) * N];
    uint2 w0; w0.x = (unsigned)ov.x; w0.y = (unsigned)ov.y;
    uint2 w1; w1.x = (unsigned)ov.z; w1.y = (unsigned)ov.w;
    *reinterpret_cast<uint2*>(&dst[C0]) = w0;
    *reinterpret_cast<uint2*>(&dst[C1]) = w1;
  }
}

// ---------- Flash attention (swapped-QK^T, in-register P, zero-shuffle PV) ----------
// Q/K [bh][N][64] (q pre-scaled, exp2 space), Vt [bh][64][N] sigma-permuted ->
// Out bf16 [B][N][1024]. 512 thr = 8 waves x 16 q-rows = 128-row tile; KVBLK=128;
// sequential dual-tile (x, 15-x): 17 uniform phases. S computed as mfma(K,Q) so a
// lane holds 32 k-scores for ONE q-row: scalar m/l, 2-shuffle max, P packed to bf16
// pairs in registers, PV = mfma(V, P) with sigma-matched V columns (no P LDS).
// l via ones-MFMA (exact bf16 consistency). ALL masking uses the finite sentinel
// -1e30f (never -inf) so every arithmetic path is NaN-free by construction.
// LDS = K dbuf 32K + V dbuf 32K = 64KB. Grid (32 bh, 8): id%8 = bh%8 -> XCD-pinned.
__global__ __launch_bounds__(512) void flash_kernel(const unsigned short* __restrict__ Q,
                                                    const unsigned short* __restrict__ Kb,
                                                    const unsigned short* __restrict__ Vt,
                                                    unsigned short* __restrict__ Out, int N) {
  extern __shared__ __align__(16) unsigned short smem[];
  unsigned short* KsB = smem;           // [2][128*64]
  unsigned short* VsB = smem + 16384;   // [2][64*128] sigma-permuted cols

  const int tid = threadIdx.x;
  const int lane = tid & 63, wave = tid >> 6;
  const int lr = lane & 15, lk = lane >> 4;
  const int bh = blockIdx.x;            // XCD pin
  const int x = blockIdx.y;             // 0..7
  const int qtA = x, qtB = 15 - x;
  const int ntA = x + 1;                // + (16-x) = 17 phases, uniform
  const unsigned short* Qh = Q + (size_t)bh * N * 64;
  const unsigned short* Kh = Kb + (size_t)bh * N * 64;
  const unsigned short* Vh = Vt + (size_t)bh * 64 * N;

  const int wrowA = qtA * 128 + wave * 16;
  const int wrowB = qtB * 128 + wave * 16;

  // staging sources (pre-swizzled) — proven layout (R6)
  const int kr = tid >> 3;
  const int kcb = ((tid & 7) * 16) ^ ((kr & 7) << 4);
  const unsigned short* Kg0 = Kh + (size_t)kr * 64 + (kcb >> 1);
  const int vr = tid >> 4;
  const int vcb = ((tid & 15) * 16) ^ ((vr & 7) << 4);
  const unsigned short* Vg0 = Vh + (size_t)vr * N + (vcb >> 1);

  auto stage = [&](int buf, int tk) {
    const unsigned short* kp = Kg0 + (size_t)tk * 8192;
    const unsigned short* vp = Vg0 + (size_t)tk * 128;
    unsigned short* kl = KsB + buf * 8192 + wave * 512;
    unsigned short* vl = VsB + buf * 8192 + wave * 512;
    gload_lds16(kp, kl);
    gload_lds16(kp + 4096, kl + 4096);
    gload_lds16(vp, vl);
    gload_lds16(vp + (size_t)32 * N, vl + 4096);
  };

  stage(0, 0);

  bf16x8 qA0 = ldfrag(&Qh[(size_t)(wrowA + lr) * 64 + lk * 8]);
  bf16x8 qA1 = ldfrag(&Qh[(size_t)(wrowA + lr) * 64 + 32 + lk * 8]);
  bf16x8 qB0 = ldfrag(&Qh[(size_t)(wrowB + lr) * 64 + lk * 8]);
  bf16x8 qB1 = ldfrag(&Qh[(size_t)(wrowB + lr) * 64 + 32 + lk * 8]);

  bf16x8 ones;
  {
    union { unsigned short u; __bf16 b; } one; one.u = 0x3F80;
#pragma unroll
    for (int j = 0; j < 8; ++j) ones[j] = one.b;
  }

  const float NEG = -1e30f;  // finite sentinel: no -inf anywhere in this kernel
  f32x4 oacc[4] = {};   // O^T: [d-tile ni][d-sub r], q = lr
  f32x4 lacc = {};      // all 4 entries = l[q]
  float m_run = NEG;

  auto compute_phase = [&](int buf, bf16x8 q0, bf16x8 q1, bool diag) {
    const unsigned short* Ksb = KsB + buf * 8192;
    const unsigned short* Vsb = VsB + buf * 8192;
    // S^T = K @ Q^T : s[ni][r] = S[k = ni*16+lk*4+r][q = lr]
    f32x4 s[8];
#pragma unroll
    for (int ni = 0; ni < 8; ++ni) s[ni] = f32x4{0.f, 0.f, 0.f, 0.f};
    __builtin_amdgcn_s_setprio(1);
#pragma unroll
    for (int ni = 0; ni < 8; ++ni) {
      const int R = ni * 16 + lr;
      const int sw = (R & 7) << 4;
      bf16x8 kf0 = ldfrag(&Ksb[R * 64 + (((lk * 16) ^ sw) >> 1)]);
      bf16x8 kf1 = ldfrag(&Ksb[R * 64 + (((64 + lk * 16) ^ sw) >> 1)]);
      s[ni] = __builtin_amdgcn_mfma_f32_16x16x32_bf16(kf0, q0, s[ni], 0, 0, 0);
      s[ni] = __builtin_amdgcn_mfma_f32_16x16x32_bf16(kf1, q1, s[ni], 0, 0, 0);
    }
    __builtin_amdgcn_s_setprio(0);

    if (diag) {  // tile-aligned diagonal: local k > local q (finite sentinel)
      const int ql = wave * 16 + lr;
#pragma unroll
      for (int ni = 0; ni < 8; ++ni)
#pragma unroll
        for (int r = 0; r < 4; ++r)
          if (ni * 16 + lk * 4 + r > ql) s[ni][r] = NEG;
    }

    // row max: 31 local fmax + 2 shuffles (lanes lr, lr+16, lr+32, lr+48 share q)
    float mx = s[0][0];
#pragma unroll
    for (int ni = 0; ni < 8; ++ni)
#pragma unroll
      for (int r = 0; r < 4; ++r)
        if (ni || r) mx = fmaxf(mx, s[ni][r]);
    mx = fmaxf(mx, __shfl_xor(mx, 16, 64));
    mx = fmaxf(mx, __shfl_xor(mx, 32, 64));

    if (!__all(mx - m_run <= 8.0f)) {  // defer-max (THR=8 in log2 units)
      float nm = fmaxf(m_run, mx);
      float alpha = __builtin_amdgcn_exp2f(m_run - nm);  // finite args -> no NaN
      m_run = nm;
#pragma unroll
      for (int ni = 0; ni < 4; ++ni) oacc[ni] *= alpha;
      lacc *= alpha;
    }

    // P = exp2(s - m), packed bf16 pairs, ALL IN REGISTERS (trunc; l uses same bits)
    unsigned pk[8][2];
#pragma unroll
    for (int ni = 0; ni < 8; ++ni) {
      float p0 = __builtin_amdgcn_exp2f(s[ni][0] - m_run);
      float p1 = __builtin_amdgcn_exp2f(s[ni][1] - m_run);
      float p2 = __builtin_amdgcn_exp2f(s[ni][2] - m_run);
      float p3 = __builtin_amdgcn_exp2f(s[ni][3] - m_run);
      pk[ni][0] = (unsigned)f2b_trunc(p0) | ((unsigned)f2b_trunc(p1) << 16);
      pk[ni][1] = (unsigned)f2b_trunc(p2) | ((unsigned)f2b_trunc(p3) << 16);
    }

    // O^T += V^T @ P^T ; l += ones @ P^T. Contraction-order sigma matches the
    // lane's own held k-values; V columns pre-permuted by vtrans.
    __builtin_amdgcn_s_setprio(1);
#pragma unroll
    for (int c = 0; c < 4; ++c) {
      union { unsigned u[4]; bf16x8 v; } pb;
      pb.u[0] = pk[2 * c][0];
      pb.u[1] = pk[2 * c][1];
      pb.u[2] = pk[2 * c + 1][0];
      pb.u[3] = pk[2 * c + 1][1];
      lacc = __builtin_amdgcn_mfma_f32_16x16x32_bf16(ones, pb.v, lacc, 0, 0, 0);
      const int cb = c * 64 + lk * 16;
#pragma unroll
      for (int ni = 0; ni < 4; ++ni) {
        const int RV = ni * 16 + lr;
        bf16x8 vf = ldfrag(&Vsb[RV * 128 + ((cb ^ ((RV & 7) << 4)) >> 1)]);
        oacc[ni] = __builtin_amdgcn_mfma_f32_16x16x32_bf16(vf, pb.v, oacc[ni], 0, 0, 0);
      }
    }
    __builtin_amdgcn_s_setprio(0);
  };

  const int b = bh >> 4, h = bh & 15;
  auto epilogue = [&](int wrow0) {
    const float rl = 1.0f / lacc[0];
    const int q = wrow0 + lr;
#pragma unroll
    for (int ni = 0; ni < 4; ++ni) {
      uint2 w;
      w.x = (unsigned)f2b(oacc[ni][0] * rl) | ((unsigned)f2b(oacc[ni][1] * rl) << 16);
      w.y = (unsigned)f2b(oacc[ni][2] * rl) | ((unsigned)f2b(oacc[ni][3] * rl) << 16);
      *reinterpret_cast<uint2*>(
          &Out[((size_t)(b * N + q)) * 1024 + h * 64 + ni * 16 + lk * 4]) = w;
    }
  };

  __syncthreads();

  int buf = 0;
  for (int p = 0; p < 17; ++p) {
    if (p + 1 < 17) {
      int tk2 = (p + 1 < ntA) ? (p + 1) : (p + 1 - ntA);
      stage(buf ^ 1, tk2);
    }
    if (p == ntA) {  // scan A done: write O_A, reset accumulators
      epilogue(wrowA);
#pragma unroll
      for (int ni = 0; ni < 4; ++ni) oacc[ni] = f32x4{0.f, 0.f, 0.f, 0.f};
      lacc = f32x4{0.f, 0.f, 0.f, 0.f};
      m_run = NEG;
    }
    if (p < ntA) compute_phase(buf, qA0, qA1, p == ntA - 1);
    else         compute_phase(buf, qB0, qB1, p == 16);
    __syncthreads();
    buf ^= 1;
  }
  epilogue(wrowB);
}

// ---------- launch ----------
extern "C" void kernel_launch(void* const* d_in, const int* in_sizes, int n_in,
                              void* d_out, int out_size, void* d_ws, size_t ws_size,
                              hipStream_t stream) {
  const int B = 2, N = 2048, E = 1024, C = 1024, NC = 3072;
  const int M = B * N;  // 4096

  const float* x  = (const float*)d_in[0];
  const float* Wq = (const float*)d_in[1];
  const float* bq = (const float*)d_in[2];
  const float* Wk = (const float*)d_in[3];
  const float* bk = (const float*)d_in[4];
  const float* Wv = (const float*)d_in[5];
  const float* bv = (const float*)d_in[6];
  const float* Wo = (const float*)d_in[7];
  const float* bo = (const float*)d_in[8];

  char* w = (char*)d_ws;
  size_t off = 0;
  auto alloc = [&](size_t bytes) {
    void* p = w + off;
    off += (bytes + 255) & ~(size_t)255;
    return p;
  };
  unsigned short* xb    = (unsigned short*)alloc((size_t)M * E * 2);
  unsigned short* wqkv  = (unsigned short*)alloc((size_t)NC * E * 2);
  unsigned short* wob   = (unsigned short*)alloc((size_t)E * C * 2);
  unsigned short* qkvb  = (unsigned short*)alloc((size_t)M * NC * 2);
  unsigned short* qb    = (unsigned short*)alloc((size_t)B * 16 * N * 64 * 2);
  unsigned short* kb    = (unsigned short*)alloc((size_t)B * 16 * N * 64 * 2);
  unsigned short* vt    = (unsigned short*)alloc((size_t)B * 16 * 64 * N * 2);
  unsigned short* attnb = (unsigned short*)alloc((size_t)M * C * 2);
  float* sin_t = (float*)alloc((size_t)N * 32 * 4);
  float* cos_t = (float*)alloc((size_t)N * 32 * 4);

  // fused bf16 casts (x, Wq, Wk, Wv, Wo) — one kernel, 2M float4 total
  cast_all_kernel<<<8192, 256, 0, stream>>>(x, Wq, Wk, Wv, Wo, xb, wqkv, wob);

  int n3 = N * 32;
  sincos_kernel<<<(n3 + 255) / 256, 256, 0, stream>>>(sin_t, cos_t, n3);

  // QKV projection: 256^2 deep-pipelined GEMM, bias select in epilogue
  static const int GEMM_LDS = 131072;
  hipFuncSetAttribute(reinterpret_cast<const void*>(gemm256),
                      hipFuncAttributeMaxDynamicSharedMemorySize, GEMM_LDS);
  gemm256<<<dim3((NC / 256) * (M / 256)), 512, GEMM_LDS, stream>>>(
      xb, wqkv, qkvb, bq, bk, bv, M, NC, E, NC / 256);

  // RoPE + layout to [bh][N][64]
  int nwaves = 2 * B * N * 16;
  rope_kernel<<<nwaves / 4, 256, 0, stream>>>(qkvb, sin_t, cos_t, qb, kb, N);

  // V transpose to [bh][64][N], sigma-permuted columns
  vtrans_kernel<<<dim3(N / 64, B * 16), 256, 0, stream>>>(qkvb, vt, N);

  // causal flash attention: 256 blocks x 512 thr, 64KB LDS, XCD-pinned bh
  static const int FLASH_LDS = 65536;
  hipFuncSetAttribute(reinterpret_cast<const void*>(flash_kernel),
                      hipFuncAttributeMaxDynamicSharedMemorySize, FLASH_LDS);
  flash_kernel<<<dim3(B * 16, 8), 512, FLASH_LDS, stream>>>(qb, kb, vt, attnb, N);

  // output projection: [4096][1024] x [1024][1024]^T + bo -> f32 d_out
  gemm_bt<1><<<dim3(E / 128, M / 128), 256, 0, stream>>>(attnb, wob, d_out, bo, M, E, C);
}

// Round 12
// 134.249 us; speedup vs baseline: 1.1513x; 1.0290x over previous
//
#include <hip/hip_runtime.h>
#include <hip/hip_bf16.h>
#include <cstdint>
#include <cstddef>

// ---------- types ----------
using bf16x8 = __attribute__((ext_vector_type(8))) __bf16;
using f32x4  = __attribute__((ext_vector_type(4))) float;

__device__ __forceinline__ float b2f(unsigned short u) {
  union { unsigned u; float f; } x; x.u = ((unsigned)u) << 16; return x.f;
}
__device__ __forceinline__ unsigned short f2b(float f) {
  union { float f; unsigned u; } x; x.f = f;
  unsigned r = x.u + 0x7fffu + ((x.u >> 16) & 1u);
  return (unsigned short)(r >> 16);
}
// truncating cast: safe for P because l is computed (via MFMA) from the SAME bf16 values.
__device__ __forceinline__ unsigned short f2b_trunc(float f) {
  union { float f; unsigned u; } x; x.f = f;
  return (unsigned short)(x.u >> 16);
}

// async global->LDS, 16B per lane. dst must be wave-uniform base (HW adds lane*16).
__device__ __forceinline__ void gload_lds16(const void* g, void* l) {
  __builtin_amdgcn_global_load_lds(
      (const __attribute__((address_space(1))) void*)g,
      (__attribute__((address_space(3))) void*)l, 16, 0, 0);
}

__device__ __forceinline__ bf16x8 ldfrag(const unsigned short* p) {
  return *reinterpret_cast<const bf16x8*>(p);
}

// ---------- fused cast: x (1M float4), Wq/Wk/Wv/Wo (256K float4 each) -> bf16 ----------
__global__ __launch_bounds__(256) void cast_all_kernel(const float* __restrict__ x,
                                                       const float* __restrict__ Wq,
                                                       const float* __restrict__ Wk,
                                                       const float* __restrict__ Wv,
                                                       const float* __restrict__ Wo,
                                                       unsigned short* __restrict__ xb,
                                                       unsigned short* __restrict__ wqkv,
                                                       unsigned short* __restrict__ wob) {
  const int i = blockIdx.x * 256 + threadIdx.x;  // float4 index, total 2M
  const int XW = 1048576;                        // x: 4096*1024 floats = 1M float4
  const int WW = 262144;                         // each W: 1024*1024 floats = 256K float4
  const float* s; unsigned short* d; int j;
  if (i < XW)                { s = x;  d = xb;              j = i; }
  else if (i < XW + WW)      { s = Wq; d = wqkv;            j = i - XW; }
  else if (i < XW + 2 * WW)  { s = Wk; d = wqkv + 1048576;  j = i - XW - WW; }
  else if (i < XW + 3 * WW)  { s = Wv; d = wqkv + 2097152;  j = i - XW - 2 * WW; }
  else                       { s = Wo; d = wob;             j = i - XW - 3 * WW; }
  float4 v = reinterpret_cast<const float4*>(s)[j];
  ushort4 o;
  o.x = f2b(v.x); o.y = f2b(v.y); o.z = f2b(v.z); o.w = f2b(v.w);
  reinterpret_cast<ushort4*>(d)[j] = o;
}

__global__ __launch_bounds__(256) void sincos_kernel(float* __restrict__ st,
                                                     float* __restrict__ ct, int total) {
  int i = blockIdx.x * 256 + threadIdx.x;
  if (i >= total) return;
  int n = i >> 5, j = i & 31;
  float inv = powf(10000.0f, -(float)j * (1.0f / 32.0f));
  float ang = (float)n * inv;
  st[i] = sinf(ang);
  ct[i] = cosf(ang);
}

// ---------- 256x256 8-wave GEMM with counted-vmcnt pipeline (qkv projection) ----------
// C[M][N] = A[M][K]*B[N][K]^T + bias(q/k/v select), bf16 in/out. BK=64, dbuf 128KB.
// T3+T4: prefetch for kt+1 issued 2 loads/phase during kt (B halves ph0/ph1,
// A Q0/Q2 ph2, A Q1/Q3 ph3); waits are COUNTED: vmcnt(4)+bar at ph2 (awaits this
// tile's A-Q1/Q3, 3 phases old), vmcnt(2)+bar at tile end (awaits kt+1's B+A02,
// leaves A13 in flight). vmcnt never 0 in steady state; 2 barriers/K-tile.
__global__ __launch_bounds__(512) void gemm256(const unsigned short* __restrict__ A,
                                               const unsigned short* __restrict__ B,
                                               unsigned short* __restrict__ C,
                                               const float* __restrict__ bq,
                                               const float* __restrict__ bk,
                                               const float* __restrict__ bv,
                                               int M, int N, int K, int TN) {
  extern __shared__ __align__(16) unsigned short sm[];  // [2][A 256x64 | B 256x64]
  const int tid = threadIdx.x, lane = tid & 63, wave = tid >> 6;
  const int lr = lane & 15, lk = lane >> 4;
  const int wr = wave >> 2, wc = wave & 3;  // 2 x 4 waves

  // XCD-bijective swizzle (grid % 8 == 0)
  int wg = (int)blockIdx.x;
  const int cpx = (int)gridDim.x >> 3;
  wg = (wg & 7) * cpx + (wg >> 3);
  const int bn = (wg % TN) * 256, bm = (wg / TN) * 256;

  // staging: issue i covers rows i*64..i*64+63; thread -> row srow, 16B chunk.
  const int srow = wave * 8 + (lane >> 3);
  const int scol = (((lane & 7) * 16) ^ (((lane >> 3) & 7) << 4)) >> 1;  // elems
  const unsigned short* Ag = A + (size_t)(bm + srow) * K + scol;
  const unsigned short* Bg = B + (size_t)(bn + srow) * K + scol;

  auto issueA = [&](int kt, int nb, int i) {
    gload_lds16(Ag + (size_t)(i * 64) * K + (size_t)kt * 64,
                sm + nb * 32768 + wave * 512 + i * 4096);
  };
  auto issueB = [&](int kt, int nb, int i) {
    gload_lds16(Bg + (size_t)(i * 64) * K + (size_t)kt * 64,
                sm + nb * 32768 + 16384 + wave * 512 + i * 4096);
  };

  f32x4 acc[8][4] = {};
  const int swz = (lr & 7) << 4;  // row&7 == lr&7 for all frag rows
  const int NT = K / 64;

  // prologue: full first tile, single drain (not steady state)
#pragma unroll
  for (int i = 0; i < 4; ++i) { issueB(0, 0, i); issueA(0, 0, i); }
  asm volatile("s_waitcnt vmcnt(0)" ::: "memory");
  __builtin_amdgcn_s_barrier();

  for (int kt = 0; kt < NT; ++kt) {
    const int cur = kt & 1, nb = cur ^ 1;
    const bool pf = (kt + 1 < NT);

    const unsigned short* Ab = sm + cur * 32768 + wr * 8192;          // wave's 128 A rows
    const unsigned short* Bb = sm + cur * 32768 + 16384 + wc * 4096;  // wave's 64 B rows

    // b-frags once per K-tile (awaited at previous tile end)
    bf16x8 b[4][2];
#pragma unroll
    for (int n = 0; n < 4; ++n)
#pragma unroll
      for (int kk = 0; kk < 2; ++kk)
        b[n][kk] = ldfrag(&Bb[(n * 16 + lr) * 64 + (((kk * 64 + lk * 16) ^ swz) >> 1)]);

#pragma unroll
    for (int q = 0; q < 4; ++q) {
      if (q == 2) {
        // await THIS tile's A-Q1/Q3 (issued 3 phases ago); 4 newer (kt+1 B) may fly
        if (pf) asm volatile("s_waitcnt vmcnt(4)" ::: "memory");
        else    asm volatile("s_waitcnt vmcnt(0)" ::: "memory");
        __builtin_amdgcn_s_barrier();
      }
      if (pf) {  // interleaved prefetch for kt+1: 2 loads per phase
        if (q == 0)      { issueB(kt + 1, nb, 0); issueB(kt + 1, nb, 1); }
        else if (q == 1) { issueB(kt + 1, nb, 2); issueB(kt + 1, nb, 3); }
        else if (q == 2) { issueA(kt + 1, nb, 0); issueA(kt + 1, nb, 2); }
        else             { issueA(kt + 1, nb, 1); issueA(kt + 1, nb, 3); }
      }
      bf16x8 a[2][2];
#pragma unroll
      for (int m = 0; m < 2; ++m)
#pragma unroll
        for (int kk = 0; kk < 2; ++kk)
          a[m][kk] = ldfrag(&Ab[((q * 2 + m) * 16 + lr) * 64 + (((kk * 64 + lk * 16) ^ swz) >> 1)]);
      __builtin_amdgcn_s_setprio(1);
#pragma unroll
      for (int kk = 0; kk < 2; ++kk)
#pragma unroll
        for (int m = 0; m < 2; ++m)
#pragma unroll
          for (int n = 0; n < 4; ++n)
            acc[q * 2 + m][n] =
                __builtin_amdgcn_mfma_f32_16x16x32_bf16(a[m][kk], b[n][kk], acc[q * 2 + m][n], 0, 0, 0);
      __builtin_amdgcn_s_setprio(0);
    }

    if (pf) {  // await kt+1's B + A-Q0/Q2; its A-Q1/Q3 (2 newest) stay in flight
      asm volatile("s_waitcnt vmcnt(2)" ::: "memory");
      __builtin_amdgcn_s_barrier();
    }
  }

  // epilogue: bias select per 1024-col third
#pragma unroll
  for (int n = 0; n < 4; ++n) {
    const int col = bn + wc * 64 + n * 16 + lr;
    const int third = col >> 10, ci = col & 1023;
    const float bvv = (third == 0) ? bq[ci] : (third == 1) ? bk[ci] : bv[ci];
#pragma unroll
    for (int m = 0; m < 8; ++m)
#pragma unroll
      for (int r = 0; r < 4; ++r) {
        const int row = bm + wr * 128 + m * 16 + lk * 4 + r;
        C[(size_t)row * N + col] = f2b(acc[m][n][r] + bvv);
      }
  }
}

// ---------- GEMM: C[M][N] = A[M][K] * B[N][K]^T (+bias), bf16 in, f32 acc ----------
template <int OUTF32>
__global__ __launch_bounds__(256) void gemm_bt(const unsigned short* __restrict__ A,
                                               const unsigned short* __restrict__ B,
                                               void* __restrict__ C,
                                               const float* __restrict__ bias,
                                               int M, int N, int K) {
  __shared__ __align__(16) unsigned short As[128 * 32];
  __shared__ __align__(16) unsigned short Bs[128 * 32];
  const int tid = threadIdx.x;
  const int lane = tid & 63, wave = tid >> 6;
  const int wr = wave >> 1, wc = wave & 1;
  const int bm = blockIdx.y * 128, bn = blockIdx.x * 128;
  const int lr = lane & 15, lk = lane >> 4;
  f32x4 acc[4][4] = {};

  for (int k0 = 0; k0 < K; k0 += 32) {
#pragma unroll
    for (int i = 0; i < 2; ++i) {
      int idx = i * 256 + tid;
      int row = idx >> 2, c8 = (idx & 3) * 8;
      gload_lds16(A + (size_t)(bm + row) * K + k0 + c8, &As[(i * 256 + wave * 64) * 8]);
      gload_lds16(B + (size_t)(bn + row) * K + k0 + c8, &Bs[(i * 256 + wave * 64) * 8]);
    }
    __syncthreads();
    bf16x8 af[4], bfr[4];
#pragma unroll
    for (int mi = 0; mi < 4; ++mi)
      af[mi] = ldfrag(&As[(wr * 64 + mi * 16 + lr) * 32 + lk * 8]);
#pragma unroll
    for (int ni = 0; ni < 4; ++ni)
      bfr[ni] = ldfrag(&Bs[(wc * 64 + ni * 16 + lr) * 32 + lk * 8]);
#pragma unroll
    for (int mi = 0; mi < 4; ++mi)
#pragma unroll
      for (int ni = 0; ni < 4; ++ni)
        acc[mi][ni] = __builtin_amdgcn_mfma_f32_16x16x32_bf16(af[mi], bfr[ni], acc[mi][ni], 0, 0, 0);
    __syncthreads();
  }

#pragma unroll
  for (int mi = 0; mi < 4; ++mi) {
#pragma unroll
    for (int ni = 0; ni < 4; ++ni) {
      int col = bn + wc * 64 + ni * 16 + lr;
      float bv = bias ? bias[col] : 0.0f;
#pragma unroll
      for (int r = 0; r < 4; ++r) {
        int row = bm + wr * 64 + mi * 16 + lk * 4 + r;
        float v = acc[mi][ni][r] + bv;
        if (OUTF32)
          reinterpret_cast<float*>(C)[(size_t)row * N + col] = v;
        else
          reinterpret_cast<unsigned short*>(C)[(size_t)row * N + col] = f2b(v);
      }
    }
  }
}

// ---------- RoPE: qkv[B*N][3072] -> Qo/Ko [B*16][N][64] ----------
// q pre-scaled by log2(e)/sqrt(D) so flash softmax runs in exp2 space.
__global__ __launch_bounds__(256) void rope_kernel(const unsigned short* __restrict__ qkv,
                                                   const float* __restrict__ st,
                                                   const float* __restrict__ ct,
                                                   unsigned short* __restrict__ Qo,
                                                   unsigned short* __restrict__ Ko, int N) {
  const int lane = threadIdx.x & 63;
  const int gw = (int)((blockIdx.x * 256 + threadIdx.x) >> 6);
  const int total = 2 * 2 * N * 16;
  if (gw >= total) return;
  const int which = gw / (2 * N * 16);  // 0=q, 1=k
  int rem = gw - which * (2 * N * 16);
  const int b = rem / (N * 16);
  rem -= b * (N * 16);
  const int n = rem >> 4, h = rem & 15;
  const int d = lane;
  float v = b2f(qkv[((size_t)(b * N + n)) * 3072 + which * 1024 + h * 64 + d]);
  const int j = d & 31;
  float c = ct[n * 32 + j], s = st[n * 32 + j];
  int partner = (d < 32) ? (2 * d + 1) : (2 * (d - 32));
  float pv = __shfl(v, partner, 64);
  float res = (d < 32) ? (v * c - pv * s) : (v * c + pv * s);
  if (which == 0) res *= 0.18033688f;  // (1/8) * log2(e)
  unsigned short* dst = which ? Ko : Qo;
  dst[(((size_t)(b * 16 + h)) * N + n) * 64 + d] = f2b(res);
}

// ---------- V transpose: qkv v-part [n][d] -> Vt[bh][d][n'] ----------
// Columns sigma-permuted within each 32-block: k = 16a + 4m + b  ->  col' = 8m + 4a + b.
__global__ __launch_bounds__(256) void vtrans_kernel(const unsigned short* __restrict__ qkv,
                                                     unsigned short* __restrict__ Vt, int N) {
  __shared__ __align__(16) unsigned short T[64][80];
  const int bh = blockIdx.y, b = bh >> 4, h = bh & 15;
  const int n0 = blockIdx.x * 64;
  const int tid = threadIdx.x;
#pragma unroll
  for (int i = 0; i < 2; ++i) {
    int idx = i * 256 + tid;
    int row = idx >> 3, c8 = (idx & 7) * 8;
    int4 v = *reinterpret_cast<const int4*>(
        &qkv[((size_t)(b * N + n0 + row)) * 3072 + 2048 + h * 64 + c8]);
    *reinterpret_cast<int4*>(&T[row][c8]) = v;
  }
  __syncthreads();
#pragma unroll
  for (int i = 0; i < 2; ++i) {
    int idx = i * 256 + tid;
    int d = idx >> 3, n8 = (idx & 7) * 8;
    int4 ov;
    ov.x = (int)T[n8 + 0][d] | ((int)T[n8 + 1][d] << 16);
    ov.y = (int)T[n8 + 2][d] | ((int)T[n8 + 3][d] << 16);
    ov.z = (int)T[n8 + 4][d] | ((int)T[n8 + 5][d] << 16);
    ov.w = (int)T[n8 + 6][d] | ((int)T[n8 + 7][d] << 16);
    // sigma-permuted destination: t=0..3 -> C0..C0+3 ; t=4..7 -> C1..C1+3
    const int a = (n8 >> 4) & 1, m0 = (n8 >> 2) & 3, b32 = n8 & 32;
    const int C0 = n0 + b32 + m0 * 8 + a * 4;
    const int C1 = C0 + 8;
    unsigned short* dst = &Vt[((size_t)bh * 64 + d) * N];
    uint2 w0; w0.x = (unsigned)ov.x; w0.y = (unsigned)ov.y;
    uint2 w1; w1.x = (unsigned)ov.z; w1.y = (unsigned)ov.w;
    *reinterpret_cast<uint2*>(&dst[C0]) = w0;
    *reinterpret_cast<uint2*>(&dst[C1]) = w1;
  }
}

// ---------- Flash attention (swapped-QK^T, in-register P, zero-shuffle PV) ----------
__global__ __launch_bounds__(512) void flash_kernel(const unsigned short* __restrict__ Q,
                                                    const unsigned short* __restrict__ Kb,
                                                    const unsigned short* __restrict__ Vt,
                                                    unsigned short* __restrict__ Out, int N) {
  extern __shared__ __align__(16) unsigned short smem[];
  unsigned short* KsB = smem;           // [2][128*64]
  unsigned short* VsB = smem + 16384;   // [2][64*128] sigma-permuted cols

  const int tid = threadIdx.x;
  const int lane = tid & 63, wave = tid >> 6;
  const int lr = lane & 15, lk = lane >> 4;
  const int bh = blockIdx.x;            // XCD pin
  const int x = blockIdx.y;             // 0..7
  const int qtA = x, qtB = 15 - x;
  const int ntA = x + 1;                // + (16-x) = 17 phases, uniform
  const unsigned short* Qh = Q + (size_t)bh * N * 64;
  const unsigned short* Kh = Kb + (size_t)bh * N * 64;
  const unsigned short* Vh = Vt + (size_t)bh * 64 * N;

  const int wrowA = qtA * 128 + wave * 16;
  const int wrowB = qtB * 128 + wave * 16;

  const int kr = tid >> 3;
  const int kcb = ((tid & 7) * 16) ^ ((kr & 7) << 4);
  const unsigned short* Kg0 = Kh + (size_t)kr * 64 + (kcb >> 1);
  const int vr = tid >> 4;
  const int vcb = ((tid & 15) * 16) ^ ((vr & 7) << 4);
  const unsigned short* Vg0 = Vh + (size_t)vr * N + (vcb >> 1);

  auto stage = [&](int buf, int tk) {
    const unsigned short* kp = Kg0 + (size_t)tk * 8192;
    const unsigned short* vp = Vg0 + (size_t)tk * 128;
    unsigned short* kl = KsB + buf * 8192 + wave * 512;
    unsigned short* vl = VsB + buf * 8192 + wave * 512;
    gload_lds16(kp, kl);
    gload_lds16(kp + 4096, kl + 4096);
    gload_lds16(vp, vl);
    gload_lds16(vp + (size_t)32 * N, vl + 4096);
  };

  stage(0, 0);

  bf16x8 qA0 = ldfrag(&Qh[(size_t)(wrowA + lr) * 64 + lk * 8]);
  bf16x8 qA1 = ldfrag(&Qh[(size_t)(wrowA + lr) * 64 + 32 + lk * 8]);
  bf16x8 qB0 = ldfrag(&Qh[(size_t)(wrowB + lr) * 64 + lk * 8]);
  bf16x8 qB1 = ldfrag(&Qh[(size_t)(wrowB + lr) * 64 + 32 + lk * 8]);

  bf16x8 ones;
  {
    union { unsigned short u; __bf16 b; } one; one.u = 0x3F80;
#pragma unroll
    for (int j = 0; j < 8; ++j) ones[j] = one.b;
  }

  const float NEG = -1e30f;  // finite sentinel: no -inf anywhere in this kernel
  f32x4 oacc[4] = {};   // O^T: [d-tile ni][d-sub r], q = lr
  f32x4 lacc = {};      // all 4 entries = l[q]
  float m_run = NEG;

  auto compute_phase = [&](int buf, bf16x8 q0, bf16x8 q1, bool diag) {
    const unsigned short* Ksb = KsB + buf * 8192;
    const unsigned short* Vsb = VsB + buf * 8192;
    f32x4 s[8];
#pragma unroll
    for (int ni = 0; ni < 8; ++ni) s[ni] = f32x4{0.f, 0.f, 0.f, 0.f};
    __builtin_amdgcn_s_setprio(1);
#pragma unroll
    for (int ni = 0; ni < 8; ++ni) {
      const int R = ni * 16 + lr;
      const int sw = (R & 7) << 4;
      bf16x8 kf0 = ldfrag(&Ksb[R * 64 + (((lk * 16) ^ sw) >> 1)]);
      bf16x8 kf1 = ldfrag(&Ksb[R * 64 + (((64 + lk * 16) ^ sw) >> 1)]);
      s[ni] = __builtin_amdgcn_mfma_f32_16x16x32_bf16(kf0, q0, s[ni], 0, 0, 0);
      s[ni] = __builtin_amdgcn_mfma_f32_16x16x32_bf16(kf1, q1, s[ni], 0, 0, 0);
    }
    __builtin_amdgcn_s_setprio(0);

    if (diag) {
      const int ql = wave * 16 + lr;
#pragma unroll
      for (int ni = 0; ni < 8; ++ni)
#pragma unroll
        for (int r = 0; r < 4; ++r)
          if (ni * 16 + lk * 4 + r > ql) s[ni][r] = NEG;
    }

    float mx = s[0][0];
#pragma unroll
    for (int ni = 0; ni < 8; ++ni)
#pragma unroll
      for (int r = 0; r < 4; ++r)
        if (ni || r) mx = fmaxf(mx, s[ni][r]);
    mx = fmaxf(mx, __shfl_xor(mx, 16, 64));
    mx = fmaxf(mx, __shfl_xor(mx, 32, 64));

    if (!__all(mx - m_run <= 8.0f)) {  // defer-max (THR=8 in log2 units)
      float nm = fmaxf(m_run, mx);
      float alpha = __builtin_amdgcn_exp2f(m_run - nm);
      m_run = nm;
#pragma unroll
      for (int ni = 0; ni < 4; ++ni) oacc[ni] *= alpha;
      lacc *= alpha;
    }

    unsigned pk[8][2];
#pragma unroll
    for (int ni = 0; ni < 8; ++ni) {
      float p0 = __builtin_amdgcn_exp2f(s[ni][0] - m_run);
      float p1 = __builtin_amdgcn_exp2f(s[ni][1] - m_run);
      float p2 = __builtin_amdgcn_exp2f(s[ni][2] - m_run);
      float p3 = __builtin_amdgcn_exp2f(s[ni][3] - m_run);
      pk[ni][0] = (unsigned)f2b_trunc(p0) | ((unsigned)f2b_trunc(p1) << 16);
      pk[ni][1] = (unsigned)f2b_trunc(p2) | ((unsigned)f2b_trunc(p3) << 16);
    }

    __builtin_amdgcn_s_setprio(1);
#pragma unroll
    for (int c = 0; c < 4; ++c) {
      union { unsigned u[4]; bf16x8 v; } pb;
      pb.u[0] = pk[2 * c][0];
      pb.u[1] = pk[2 * c][1];
      pb.u[2] = pk[2 * c + 1][0];
      pb.u[3] = pk[2 * c + 1][1];
      lacc = __builtin_amdgcn_mfma_f32_16x16x32_bf16(ones, pb.v, lacc, 0, 0, 0);
      const int cb = c * 64 + lk * 16;
#pragma unroll
      for (int ni = 0; ni < 4; ++ni) {
        const int RV = ni * 16 + lr;
        bf16x8 vf = ldfrag(&Vsb[RV * 128 + ((cb ^ ((RV & 7) << 4)) >> 1)]);
        oacc[ni] = __builtin_amdgcn_mfma_f32_16x16x32_bf16(vf, pb.v, oacc[ni], 0, 0, 0);
      }
    }
    __builtin_amdgcn_s_setprio(0);
  };

  const int b = bh >> 4, h = bh & 15;
  auto epilogue = [&](int wrow0) {
    const float rl = 1.0f / lacc[0];
    const int q = wrow0 + lr;
#pragma unroll
    for (int ni = 0; ni < 4; ++ni) {
      uint2 w;
      w.x = (unsigned)f2b(oacc[ni][0] * rl) | ((unsigned)f2b(oacc[ni][1] * rl) << 16);
      w.y = (unsigned)f2b(oacc[ni][2] * rl) | ((unsigned)f2b(oacc[ni][3] * rl) << 16);
      *reinterpret_cast<uint2*>(
          &Out[((size_t)(b * N + q)) * 1024 + h * 64 + ni * 16 + lk * 4]) = w;
    }
  };

  __syncthreads();

  int buf = 0;
  for (int p = 0; p < 17; ++p) {
    if (p + 1 < 17) {
      int tk2 = (p + 1 < ntA) ? (p + 1) : (p + 1 - ntA);
      stage(buf ^ 1, tk2);
    }
    if (p == ntA) {
      epilogue(wrowA);
#pragma unroll
      for (int ni = 0; ni < 4; ++ni) oacc[ni] = f32x4{0.f, 0.f, 0.f, 0.f};
      lacc = f32x4{0.f, 0.f, 0.f, 0.f};
      m_run = NEG;
    }
    if (p < ntA) compute_phase(buf, qA0, qA1, p == ntA - 1);
    else         compute_phase(buf, qB0, qB1, p == 16);
    __syncthreads();
    buf ^= 1;
  }
  epilogue(wrowB);
}

// ---------- launch ----------
extern "C" void kernel_launch(void* const* d_in, const int* in_sizes, int n_in,
                              void* d_out, int out_size, void* d_ws, size_t ws_size,
                              hipStream_t stream) {
  const int B = 2, N = 2048, E = 1024, C = 1024, NC = 3072;
  const int M = B * N;  // 4096

  const float* x  = (const float*)d_in[0];
  const float* Wq = (const float*)d_in[1];
  const float* bq = (const float*)d_in[2];
  const float* Wk = (const float*)d_in[3];
  const float* bk = (const float*)d_in[4];
  const float* Wv = (const float*)d_in[5];
  const float* bv = (const float*)d_in[6];
  const float* Wo = (const float*)d_in[7];
  const float* bo = (const float*)d_in[8];

  char* w = (char*)d_ws;
  size_t off = 0;
  auto alloc = [&](size_t bytes) {
    void* p = w + off;
    off += (bytes + 255) & ~(size_t)255;
    return p;
  };
  unsigned short* xb    = (unsigned short*)alloc((size_t)M * E * 2);
  unsigned short* wqkv  = (unsigned short*)alloc((size_t)NC * E * 2);
  unsigned short* wob   = (unsigned short*)alloc((size_t)E * C * 2);
  unsigned short* qkvb  = (unsigned short*)alloc((size_t)M * NC * 2);
  unsigned short* qb    = (unsigned short*)alloc((size_t)B * 16 * N * 64 * 2);
  unsigned short* kb    = (unsigned short*)alloc((size_t)B * 16 * N * 64 * 2);
  unsigned short* vt    = (unsigned short*)alloc((size_t)B * 16 * 64 * N * 2);
  unsigned short* attnb = (unsigned short*)alloc((size_t)M * C * 2);
  float* sin_t = (float*)alloc((size_t)N * 32 * 4);
  float* cos_t = (float*)alloc((size_t)N * 32 * 4);

  // fused bf16 casts (x, Wq, Wk, Wv, Wo) — one kernel, 2M float4 total
  cast_all_kernel<<<8192, 256, 0, stream>>>(x, Wq, Wk, Wv, Wo, xb, wqkv, wob);

  int n3 = N * 32;
  sincos_kernel<<<(n3 + 255) / 256, 256, 0, stream>>>(sin_t, cos_t, n3);

  // QKV projection: 256^2 counted-vmcnt GEMM, bias select in epilogue
  static const int GEMM_LDS = 131072;
  hipFuncSetAttribute(reinterpret_cast<const void*>(gemm256),
                      hipFuncAttributeMaxDynamicSharedMemorySize, GEMM_LDS);
  gemm256<<<dim3((NC / 256) * (M / 256)), 512, GEMM_LDS, stream>>>(
      xb, wqkv, qkvb, bq, bk, bv, M, NC, E, NC / 256);

  // RoPE + layout to [bh][N][64]
  int nwaves = 2 * B * N * 16;
  rope_kernel<<<nwaves / 4, 256, 0, stream>>>(qkvb, sin_t, cos_t, qb, kb, N);

  // V transpose to [bh][64][N], sigma-permuted columns
  vtrans_kernel<<<dim3(N / 64, B * 16), 256, 0, stream>>>(qkvb, vt, N);

  // causal flash attention: 256 blocks x 512 thr, 64KB LDS, XCD-pinned bh
  static const int FLASH_LDS = 65536;
  hipFuncSetAttribute(reinterpret_cast<const void*>(flash_kernel),
                      hipFuncAttributeMaxDynamicSharedMemorySize, FLASH_LDS);
  flash_kernel<<<dim3(B * 16, 8), 512, FLASH_LDS, stream>>>(qb, kb, vt, attnb, N);

  // output projection: [4096][1024] x [1024][1024]^T + bo -> f32 d_out
  gemm_bt<1><<<dim3(E / 128, M / 128), 256, 0, stream>>>(attnb, wob, d_out, bo, M, E, C);
}